// Round 2
// baseline (928.699 us; speedup 1.0000x reference)
//
#include <hip/hip_runtime.h>
#include <hip/hip_bf16.h>

#define NN 100000
#define NE 1600000
#define DIM 128

// ---------------- CSR build ----------------

__global__ __launch_bounds__(256) void hist_k(const int* __restrict__ dst,
                                              int* __restrict__ cnt, int n) {
  int i = blockIdx.x * blockDim.x + threadIdx.x;
  int stride = gridDim.x * blockDim.x;
  for (; i < n; i += stride) atomicAdd(&cnt[dst[i]], 1);
}

__global__ __launch_bounds__(1024) void scan_k(const int* __restrict__ cnt,
                                               int* __restrict__ off, int n) {
  const int t = threadIdx.x;
  const int CH = (n + 1023) >> 10;           // 98 for n=100000
  const int b = t * CH, e = min(b + CH, n);
  int s = 0;
  for (int i = b; i < e; ++i) s += cnt[i];
  const int lane = t & 63, w = t >> 6;
  int v = s;
  #pragma unroll
  for (int d = 1; d < 64; d <<= 1) {
    int u = __shfl_up(v, d);
    if (lane >= d) v += u;
  }
  __shared__ int wsum[16];
  if (lane == 63) wsum[w] = v;
  __syncthreads();
  if (w == 0 && lane < 16) {
    int x = wsum[lane];
    #pragma unroll
    for (int d = 1; d < 16; d <<= 1) {
      int u = __shfl_up(x, d);
      if (lane >= d) x += u;
    }
    wsum[lane] = x;
  }
  __syncthreads();
  int base = (w > 0 ? wsum[w - 1] : 0) + v - s;  // exclusive prefix for this thread
  int p = base;
  for (int i = b; i < e; ++i) { off[i] = p; p += cnt[i]; }
}

__global__ __launch_bounds__(256) void scatter_k(const int* __restrict__ dst,
                                                 const int* __restrict__ off,
                                                 int* __restrict__ wcnt,
                                                 int* __restrict__ perm, int n) {
  int i = blockIdx.x * blockDim.x + threadIdx.x;
  int stride = gridDim.x * blockDim.x;
  for (; i < n; i += stride) {
    int d = dst[i];
    int p = atomicAdd(&wcnt[d], 1);
    perm[off[d] + p] = i;
  }
}

// ---------------- GEMM (x @ W) + fused attention dots ----------------
// out feat[N,128]; el[n,h] = sum_f feat[n,h,f]*al[h,f]; er likewise.
// H = number of heads (4 for layer1, 1 for layer2); H*F == 128 both layers.

template <int H>
__global__ __launch_bounds__(256) void gemm_attn_k(
    const float* __restrict__ x, const float* __restrict__ W,
    const float* __restrict__ al, const float* __restrict__ ar,
    float* __restrict__ feat, float* __restrict__ el, float* __restrict__ er,
    int n) {
  __shared__ float sW[DIM * DIM];   // 64 KB
  __shared__ float sx[16 * DIM];    // 8 KB
  const int tid = threadIdx.x;
  for (int i = tid; i < DIM * DIM / 4; i += 256)
    ((float4*)sW)[i] = ((const float4*)W)[i];
  const int row0 = blockIdx.x * 16;
  for (int i = tid; i < 16 * DIM / 4; i += 256) {
    int r = i >> 5;
    int gr = row0 + r;
    float4 v = make_float4(0.f, 0.f, 0.f, 0.f);
    if (gr < n) v = ((const float4*)(x + (size_t)gr * DIM))[i & 31];
    ((float4*)sx)[i] = v;
  }
  __syncthreads();
  const int r = tid >> 5;   // 0..7 (handles rows r and r+8)
  const int c = tid & 31;   // 4-col group
  float4 a0 = make_float4(0.f, 0.f, 0.f, 0.f);
  float4 a1 = a0;
  #pragma unroll 4
  for (int k = 0; k < DIM; ++k) {
    float4 wv = ((const float4*)(sW + k * DIM))[c];
    float x0 = sx[r * DIM + k];
    float x1 = sx[(r + 8) * DIM + k];
    a0.x = fmaf(x0, wv.x, a0.x); a0.y = fmaf(x0, wv.y, a0.y);
    a0.z = fmaf(x0, wv.z, a0.z); a0.w = fmaf(x0, wv.w, a0.w);
    a1.x = fmaf(x1, wv.x, a1.x); a1.y = fmaf(x1, wv.y, a1.y);
    a1.z = fmaf(x1, wv.z, a1.z); a1.w = fmaf(x1, wv.w, a1.w);
  }
  const int gr0 = row0 + r, gr1 = row0 + r + 8;
  if (gr0 < n) ((float4*)(feat + (size_t)gr0 * DIM))[c] = a0;
  if (gr1 < n) ((float4*)(feat + (size_t)gr1 * DIM))[c] = a1;

  // fused attention dot products
  float4 alv = ((const float4*)al)[c];
  float4 arv = ((const float4*)ar)[c];
  float pl0 = a0.x * alv.x + a0.y * alv.y + a0.z * alv.z + a0.w * alv.w;
  float pr0 = a0.x * arv.x + a0.y * arv.y + a0.z * arv.z + a0.w * arv.w;
  float pl1 = a1.x * alv.x + a1.y * alv.y + a1.z * alv.z + a1.w * alv.w;
  float pr1 = a1.x * arv.x + a1.y * arv.y + a1.z * arv.z + a1.w * arv.w;
  const int HB = 32 / H;  // threads per head
  #pragma unroll
  for (int d = 1; d < HB; d <<= 1) {
    pl0 += __shfl_xor(pl0, d); pr0 += __shfl_xor(pr0, d);
    pl1 += __shfl_xor(pl1, d); pr1 += __shfl_xor(pr1, d);
  }
  if ((c & (HB - 1)) == 0) {
    int h = c / HB;
    if (gr0 < n) { el[gr0 * H + h] = pl0; er[gr0 * H + h] = pr0; }
    if (gr1 < n) { el[gr1 * H + h] = pl1; er[gr1 * H + h] = pr1; }
  }
}

// ---------------- edge softmax + aggregate, layer 1 (H=4, F=32) ----------------
// one wave per destination node; CSR gives its incoming edges.

__global__ __launch_bounds__(256) void edge1_k(
    const float* __restrict__ feat, const float* __restrict__ el,
    const float* __restrict__ er, const float* __restrict__ bias,
    const int* __restrict__ off, const int* __restrict__ cnt,
    const int* __restrict__ perm, const int* __restrict__ src,
    float* __restrict__ hout, int n_nodes) {
  const int wid = (int)((blockIdx.x * blockDim.x + threadIdx.x) >> 6);
  const int lane = threadIdx.x & 63;
  if (wid >= n_nodes) return;
  const int start = off[wid], deg = cnt[wid];
  const int eL = lane >> 2, hh = lane & 3;  // pass-A layout: 16 edges x 4 heads
  const float er_h = er[wid * 4 + hh];
  const int h2 = lane >> 4;                 // pass-B head (f-slice 2*lane)
  const int f0 = lane * 2;
  float acc0 = 0.f, acc1 = 0.f, s_part = 0.f;
  for (int c0 = 0; c0 < deg; c0 += 16) {
    int i = c0 + eL;
    int sidx = 0; float w = 0.f;
    if (i < deg) {
      int e = perm[start + i];
      sidx = src[e];
      float v = el[sidx * 4 + hh] + er_h;
      v = (v >= 0.f) ? v : 0.2f * v;
      w = __expf(v);   // no max-subtraction: e bounded ~|8|, exp safe
    }
    s_part += w;
    int m = min(16, deg - c0);
    for (int j = 0; j < m; ++j) {
      int se = __shfl(sidx, j * 4);
      float we = __shfl(w, j * 4 + h2);
      float2 f = *(const float2*)(feat + (size_t)se * DIM + f0);
      acc0 = fmaf(we, f.x, acc0);
      acc1 = fmaf(we, f.y, acc1);
    }
  }
  #pragma unroll
  for (int d = 4; d < 64; d <<= 1) s_part += __shfl_xor(s_part, d);
  float s_tot = __shfl(s_part, h2);  // lane h (h<4) holds head-h total
  float inv = (deg > 0) ? 1.0f / s_tot : 0.f;
  float2 bv = *(const float2*)(bias + f0);
  float o0 = fmaxf(fmaf(acc0, inv, bv.x), 0.f);
  float o1 = fmaxf(fmaf(acc1, inv, bv.y), 0.f);
  *(float2*)(hout + (size_t)wid * DIM + f0) = make_float2(o0, o1);
}

// ---------------- edge softmax + aggregate, layer 2 (H=1, F=128) + fused FC ----------------

__global__ __launch_bounds__(256) void edge2_k(
    const float* __restrict__ feat, const float* __restrict__ el,
    const float* __restrict__ er, const float* __restrict__ bias,
    const float* __restrict__ fcW, const float* __restrict__ fcb,
    const float* __restrict__ thres,
    const int* __restrict__ off, const int* __restrict__ cnt,
    const int* __restrict__ perm, const int* __restrict__ src,
    float* __restrict__ out, int n_nodes) {
  const int wid = (int)((blockIdx.x * blockDim.x + threadIdx.x) >> 6);
  const int lane = threadIdx.x & 63;
  if (wid >= n_nodes) return;
  const int start = off[wid], deg = cnt[wid];
  const float ern = er[wid];
  const int f0 = lane * 2;
  float acc0 = 0.f, acc1 = 0.f, s_part = 0.f;
  for (int c0 = 0; c0 < deg; c0 += 64) {
    int i = c0 + lane;
    int sidx = 0; float w = 0.f;
    if (i < deg) {
      int e = perm[start + i];
      sidx = src[e];
      float v = el[sidx] + ern;
      v = (v >= 0.f) ? v : 0.2f * v;
      w = __expf(v);
    }
    s_part += w;
    int m = min(64, deg - c0);
    for (int j = 0; j < m; ++j) {
      int se = __shfl(sidx, j);
      float we = __shfl(w, j);
      float2 f = *(const float2*)(feat + (size_t)se * DIM + f0);
      acc0 = fmaf(we, f.x, acc0);
      acc1 = fmaf(we, f.y, acc1);
    }
  }
  #pragma unroll
  for (int d = 1; d < 64; d <<= 1) s_part += __shfl_xor(s_part, d);
  float inv = (deg > 0) ? 1.f / s_part : 0.f;
  float o0 = fmaf(acc0, inv, bias[f0]);
  float o1 = fmaf(acc1, inv, bias[f0 + 1]);
  float p = o0 * fcW[f0] + o1 * fcW[f0 + 1];
  #pragma unroll
  for (int d = 1; d < 64; d <<= 1) p += __shfl_xor(p, d);
  if (lane == 0) out[wid] = p + fcb[0] - thres[0];
}

// ---------------- launch ----------------

extern "C" void kernel_launch(void* const* d_in, const int* in_sizes, int n_in,
                              void* d_out, int out_size, void* d_ws, size_t ws_size,
                              hipStream_t stream) {
  const float* features = (const float*)d_in[0];
  const float* W1   = (const float*)d_in[1];
  const float* al1  = (const float*)d_in[2];
  const float* ar1  = (const float*)d_in[3];
  const float* b1   = (const float*)d_in[4];
  const float* W2   = (const float*)d_in[5];
  const float* al2  = (const float*)d_in[6];
  const float* ar2  = (const float*)d_in[7];
  const float* b2   = (const float*)d_in[8];
  const float* fcW  = (const float*)d_in[9];
  const float* fcb  = (const float*)d_in[10];
  const float* thr  = (const float*)d_in[11];
  const int*   src  = (const int*)d_in[12];
  const int*   dst  = (const int*)d_in[13];
  float* out = (float*)d_out;

  char* ws = (char*)d_ws;
  size_t o = 0;
  auto alloc = [&](size_t bytes) -> void* {
    void* p = (void*)(ws + o);
    o += (bytes + 255) & ~(size_t)255;
    return p;
  };
  float* feat1 = (float*)alloc((size_t)NN * DIM * 4);  // reused as feat2
  float* h     = (float*)alloc((size_t)NN * DIM * 4);
  float* el1   = (float*)alloc((size_t)NN * 4 * 4);
  float* er1   = (float*)alloc((size_t)NN * 4 * 4);
  float* el2   = (float*)alloc((size_t)NN * 4);
  float* er2   = (float*)alloc((size_t)NN * 4);
  int* cnt  = (int*)alloc((size_t)NN * 4);
  int* wcnt = (int*)alloc((size_t)NN * 4);
  int* offs = (int*)alloc((size_t)NN * 4);
  int* perm = (int*)alloc((size_t)NE * 4);

  hipMemsetAsync(cnt, 0, (size_t)NN * 4, stream);
  hipMemsetAsync(wcnt, 0, (size_t)NN * 4, stream);

  hist_k<<<1024, 256, 0, stream>>>(dst, cnt, NE);
  gemm_attn_k<4><<<(NN + 15) / 16, 256, 0, stream>>>(features, W1, al1, ar1,
                                                     feat1, el1, er1, NN);
  scan_k<<<1, 1024, 0, stream>>>(cnt, offs, NN);
  scatter_k<<<1024, 256, 0, stream>>>(dst, offs, wcnt, perm, NE);
  edge1_k<<<(NN * 64) / 256, 256, 0, stream>>>(feat1, el1, er1, b1, offs, cnt,
                                               perm, src, h, NN);
  gemm_attn_k<1><<<(NN + 15) / 16, 256, 0, stream>>>(h, W2, al2, ar2,
                                                     feat1, el2, er2, NN);
  edge2_k<<<(NN * 64) / 256, 256, 0, stream>>>(feat1, el2, er2, b2, fcW, fcb,
                                               thr, offs, cnt, perm, src, out, NN);
}

// Round 6
// 771.741 us; speedup vs baseline: 1.2034x; 1.2034x over previous
//
#include <hip/hip_runtime.h>
#include <hip/hip_bf16.h>

#define NN 100000
#define NE 1600000
#define DIM 128

typedef _Float16 f16;
struct alignas(16) h8 { f16 v[8]; };

// ---------------- CSR build ----------------

__global__ __launch_bounds__(256) void hist_k(const int* __restrict__ dst,
                                              int* __restrict__ cnt, int n) {
  int i = blockIdx.x * blockDim.x + threadIdx.x;
  int stride = gridDim.x * blockDim.x;
  for (; i < n; i += stride) atomicAdd(&cnt[dst[i]], 1);
}

__global__ __launch_bounds__(1024) void scan_k(const int* __restrict__ cnt,
                                               int* __restrict__ off, int n) {
  const int t = threadIdx.x;
  const int CH = (n + 1023) >> 10;
  const int b = t * CH, e = min(b + CH, n);
  int s = 0;
  for (int i = b; i < e; ++i) s += cnt[i];
  const int lane = t & 63, w = t >> 6;
  int v = s;
  #pragma unroll
  for (int d = 1; d < 64; d <<= 1) {
    int u = __shfl_up(v, d);
    if (lane >= d) v += u;
  }
  __shared__ int wsum[16];
  if (lane == 63) wsum[w] = v;
  __syncthreads();
  if (w == 0 && lane < 16) {
    int x = wsum[lane];
    #pragma unroll
    for (int d = 1; d < 16; d <<= 1) {
      int u = __shfl_up(x, d);
      if (lane >= d) x += u;
    }
    wsum[lane] = x;
  }
  __syncthreads();
  int base = (w > 0 ? wsum[w - 1] : 0) + v - s;
  int p = base;
  for (int i = b; i < e; ++i) { off[i] = p; p += cnt[i]; }
}

__global__ __launch_bounds__(256) void scatter_k(const int* __restrict__ dst,
                                                 const int* __restrict__ off,
                                                 int* __restrict__ wcnt,
                                                 int* __restrict__ perm, int n) {
  int i = blockIdx.x * blockDim.x + threadIdx.x;
  int stride = gridDim.x * blockDim.x;
  for (; i < n; i += stride) {
    int d = dst[i];
    int p = atomicAdd(&wcnt[d], 1);
    perm[off[d] + p] = i;
  }
}

// ---------------- GEMM (x @ W) + fused attention dots, fp16 feat out ------
// 128 rows/block, 256 threads; thread (rt=tid>>4, ct=tid&15) computes an
// 8x8 tile (rows rt*8.., cols ct*8..).  LDS 67KB (fp16 W + fp16 x) ->
// 2 blocks/CU.  x-reads: 4 distinct banks + broadcast (free); W-read: one
// 16B h8 per k, 2-way (free).

template <int H>
__global__ __launch_bounds__(256) void gemm_attn_k(
    const float* __restrict__ x, const float* __restrict__ W,
    const float* __restrict__ al, const float* __restrict__ ar,
    f16* __restrict__ feat, float* __restrict__ el, float* __restrict__ er,
    int n) {
  __shared__ f16 sW[DIM * DIM];   // 32 KB, [k][n]
  __shared__ f16 sx[DIM * 133];   // 34 KB, [r][k] stride 133
  const int tid = threadIdx.x;
  const int row0 = blockIdx.x * DIM;
  for (int i = tid; i < DIM * 32; i += 256) {
    float4 v = ((const float4*)W)[i];
    f16* p = sW + i * 4;
    p[0] = (f16)v.x; p[1] = (f16)v.y; p[2] = (f16)v.z; p[3] = (f16)v.w;
  }
  for (int i = tid; i < DIM * 32; i += 256) {
    int r = i >> 5, c4 = (i & 31) * 4;
    int gr = row0 + r;
    float4 v = make_float4(0.f, 0.f, 0.f, 0.f);
    if (gr < n) v = ((const float4*)(x + (size_t)gr * DIM))[i & 31];
    f16* p = sx + r * 133 + c4;
    p[0] = (f16)v.x; p[1] = (f16)v.y; p[2] = (f16)v.z; p[3] = (f16)v.w;
  }
  __syncthreads();
  const int rt = tid >> 4, ct = tid & 15;
  float acc[8][8];
  #pragma unroll
  for (int j = 0; j < 8; ++j)
    #pragma unroll
    for (int c = 0; c < 8; ++c) acc[j][c] = 0.f;
  const f16* xb = sx + rt * 8 * 133;
  const f16* wb = sW + ct * 8;
  #pragma unroll 2
  for (int k = 0; k < DIM; ++k) {
    float xv[8];
    #pragma unroll
    for (int j = 0; j < 8; ++j) xv[j] = (float)xb[j * 133 + k];
    h8 wv = *(const h8*)(wb + k * DIM);
    float wf[8];
    #pragma unroll
    for (int c = 0; c < 8; ++c) wf[c] = (float)wv.v[c];
    #pragma unroll
    for (int j = 0; j < 8; ++j)
      #pragma unroll
      for (int c = 0; c < 8; ++c)
        acc[j][c] = fmaf(xv[j], wf[c], acc[j][c]);
  }
  // epilogue: fp16 feat store + attention dot reductions
  float alv[8], arv[8];
  #pragma unroll
  for (int c = 0; c < 8; ++c) { alv[c] = al[ct * 8 + c]; arv[c] = ar[ct * 8 + c]; }
  const int RED = (H == 4) ? 4 : 16;  // ct-group size per head
  const int gbase = row0 + rt * 8;
  #pragma unroll
  for (int j = 0; j < 8; ++j) {
    int gr = gbase + j;
    bool ok = gr < n;
    h8 o;
    float pl = 0.f, pr = 0.f;
    #pragma unroll
    for (int c = 0; c < 8; ++c) {
      o.v[c] = (f16)acc[j][c];
      pl = fmaf(acc[j][c], alv[c], pl);
      pr = fmaf(acc[j][c], arv[c], pr);
    }
    if (ok) *(h8*)(feat + (size_t)gr * DIM + ct * 8) = o;
    #pragma unroll
    for (int d = 1; d < RED; d <<= 1) {
      pl += __shfl_xor(pl, d);
      pr += __shfl_xor(pr, d);
    }
    if (ok && (ct % RED) == 0) {
      int hh = ct / RED;
      el[gr * H + hh] = pl;
      er[gr * H + hh] = pr;
    }
  }
}

// ---------------- edge softmax + aggregate, layer 1 (H=4, F=32) ----------
// one wave/node; 16-edge chunks; fixed-trip unrolled gather for MLP.

__global__ __launch_bounds__(256) void edge1_k(
    const f16* __restrict__ feat, const float* __restrict__ el,
    const float* __restrict__ er, const float* __restrict__ bias,
    const int* __restrict__ off, const int* __restrict__ cnt,
    const int* __restrict__ perm, const int* __restrict__ src,
    float* __restrict__ hout, int n_nodes) {
  const int wid = (int)((blockIdx.x * blockDim.x + threadIdx.x) >> 6);
  const int lane = threadIdx.x & 63;
  if (wid >= n_nodes) return;
  const int start = off[wid], deg = cnt[wid];
  const int eL = lane >> 2, hh = lane & 3;   // weight phase: 16 edges x 4 heads
  const float er_h = er[wid * 4 + hh];
  const int h2 = lane >> 4;                  // gather phase: head (f-slice 2*lane)
  const int f0 = lane * 2;
  float acc0 = 0.f, acc1 = 0.f, s_part = 0.f;
  for (int c0 = 0; c0 < deg; c0 += 16) {
    int i = c0 + eL;
    bool val = i < deg;
    int e = perm[start + (val ? i : 0)];
    int sidx = val ? src[e] : 0;
    float v = el[sidx * 4 + hh] + er_h;
    v = (v >= 0.f) ? v : 0.2f * v;
    float w = val ? __expf(v) : 0.f;
    s_part += w;
    #pragma unroll
    for (int j = 0; j < 16; ++j) {
      int se = __shfl(sidx, j * 4);
      float we = __shfl(w, j * 4 + h2);
      union { unsigned u; f16 h[2]; } cv;
      cv.u = *(const unsigned*)(feat + (size_t)se * DIM + f0);
      acc0 = fmaf(we, (float)cv.h[0], acc0);
      acc1 = fmaf(we, (float)cv.h[1], acc1);
    }
  }
  #pragma unroll
  for (int d = 4; d < 64; d <<= 1) s_part += __shfl_xor(s_part, d);
  float s_tot = __shfl(s_part, h2);  // lane h2 (<4) has eL==0, hh==h2
  float inv = (deg > 0) ? 1.0f / s_tot : 0.f;
  float2 bv = *(const float2*)(bias + f0);
  float o0 = fmaxf(fmaf(acc0, inv, bv.x), 0.f);
  float o1 = fmaxf(fmaf(acc1, inv, bv.y), 0.f);
  *(float2*)(hout + (size_t)wid * DIM + f0) = make_float2(o0, o1);
}

// ---------------- edge softmax + aggregate, layer 2 (H=1) + fused FC -----

__global__ __launch_bounds__(256) void edge2_k(
    const f16* __restrict__ feat, const float* __restrict__ el,
    const float* __restrict__ er, const float* __restrict__ bias,
    const float* __restrict__ fcW, const float* __restrict__ fcb,
    const float* __restrict__ thres,
    const int* __restrict__ off, const int* __restrict__ cnt,
    const int* __restrict__ perm, const int* __restrict__ src,
    float* __restrict__ out, int n_nodes) {
  const int wid = (int)((blockIdx.x * blockDim.x + threadIdx.x) >> 6);
  const int lane = threadIdx.x & 63;
  if (wid >= n_nodes) return;
  const int start = off[wid], deg = cnt[wid];
  const float ern = er[wid];
  const int eI = lane & 15;
  const int f0 = lane * 2;
  float acc0 = 0.f, acc1 = 0.f, s_part = 0.f;
  for (int c0 = 0; c0 < deg; c0 += 16) {
    int i = c0 + eI;
    bool val = i < deg;
    int e = perm[start + (val ? i : 0)];
    int sidx = val ? src[e] : 0;
    float v = el[sidx] + ern;
    v = (v >= 0.f) ? v : 0.2f * v;
    float w = val ? __expf(v) : 0.f;
    s_part += w;
    #pragma unroll
    for (int j = 0; j < 16; ++j) {
      int se = __shfl(sidx, j);
      float we = __shfl(w, j);
      union { unsigned u; f16 h[2]; } cv;
      cv.u = *(const unsigned*)(feat + (size_t)se * DIM + f0);
      acc0 = fmaf(we, (float)cv.h[0], acc0);
      acc1 = fmaf(we, (float)cv.h[1], acc1);
    }
  }
  #pragma unroll
  for (int d = 1; d < 16; d <<= 1) s_part += __shfl_xor(s_part, d);
  float inv = (deg > 0) ? 1.f / s_part : 0.f;
  float o0 = fmaf(acc0, inv, bias[f0]);
  float o1 = fmaf(acc1, inv, bias[f0 + 1]);
  float p = o0 * fcW[f0] + o1 * fcW[f0 + 1];
  #pragma unroll
  for (int d = 1; d < 64; d <<= 1) p += __shfl_xor(p, d);
  if (lane == 0) out[wid] = p + fcb[0] - thres[0];
}

// ---------------- launch ----------------

extern "C" void kernel_launch(void* const* d_in, const int* in_sizes, int n_in,
                              void* d_out, int out_size, void* d_ws, size_t ws_size,
                              hipStream_t stream) {
  const float* features = (const float*)d_in[0];
  const float* W1   = (const float*)d_in[1];
  const float* al1  = (const float*)d_in[2];
  const float* ar1  = (const float*)d_in[3];
  const float* b1   = (const float*)d_in[4];
  const float* W2   = (const float*)d_in[5];
  const float* al2  = (const float*)d_in[6];
  const float* ar2  = (const float*)d_in[7];
  const float* b2   = (const float*)d_in[8];
  const float* fcW  = (const float*)d_in[9];
  const float* fcb  = (const float*)d_in[10];
  const float* thr  = (const float*)d_in[11];
  const int*   src  = (const int*)d_in[12];
  const int*   dst  = (const int*)d_in[13];
  float* out = (float*)d_out;

  char* ws = (char*)d_ws;
  size_t o = 0;
  auto alloc = [&](size_t bytes) -> void* {
    void* p = (void*)(ws + o);
    o += (bytes + 255) & ~(size_t)255;
    return p;
  };
  f16*   feat = (f16*)alloc((size_t)NN * DIM * 2);   // layer1 feat, reused layer2
  float* h    = (float*)alloc((size_t)NN * DIM * 4); // layer1 output (fp32)
  float* el1  = (float*)alloc((size_t)NN * 4 * 4);
  float* er1  = (float*)alloc((size_t)NN * 4 * 4);
  float* el2  = (float*)alloc((size_t)NN * 4);
  float* er2  = (float*)alloc((size_t)NN * 4);
  int* cnt  = (int*)alloc((size_t)NN * 4);
  int* wcnt = (int*)alloc((size_t)NN * 4);
  int* offs = (int*)alloc((size_t)NN * 4);
  int* perm = (int*)alloc((size_t)NE * 4);

  hipMemsetAsync(cnt, 0, (size_t)NN * 4, stream);
  hipMemsetAsync(wcnt, 0, (size_t)NN * 4, stream);

  const int GB = (NN + DIM - 1) / DIM;  // 782 blocks for GEMM
  hist_k<<<1024, 256, 0, stream>>>(dst, cnt, NE);
  gemm_attn_k<4><<<GB, 256, 0, stream>>>(features, W1, al1, ar1, feat, el1, er1, NN);
  scan_k<<<1, 1024, 0, stream>>>(cnt, offs, NN);
  scatter_k<<<1024, 256, 0, stream>>>(dst, offs, wcnt, perm, NE);
  edge1_k<<<(NN * 64) / 256, 256, 0, stream>>>(feat, el1, er1, b1, offs, cnt,
                                               perm, src, h, NN);
  gemm_attn_k<1><<<GB, 256, 0, stream>>>(h, W2, al2, ar2, feat, el2, er2, NN);
  edge2_k<<<(NN * 64) / 256, 256, 0, stream>>>(feat, el2, er2, b2, fcW, fcb,
                                               thr, offs, cnt, perm, src, out, NN);
}

// Round 10
// 650.047 us; speedup vs baseline: 1.4287x; 1.1872x over previous
//
#include <hip/hip_runtime.h>
#include <hip/hip_bf16.h>

#define NN 100000
#define NE 1600000
#define DIM 128
#define SCH 1024                      // scan chunk (elements per block)
#define NSB ((NN + SCH - 1) / SCH)    // 98 scan blocks

typedef _Float16 f16;
struct alignas(16) h8 { f16 v[8]; };

// ---------------- CSR build ----------------

__global__ __launch_bounds__(256) void hist_k(const int* __restrict__ dst,
                                              int* __restrict__ cnt, int n) {
  int i = blockIdx.x * blockDim.x + threadIdx.x;
  int stride = gridDim.x * blockDim.x;
  for (; i < n; i += stride) atomicAdd(&cnt[dst[i]], 1);
}

// Phase A: per-chunk sums (98 blocks x 256 thr, 4 elem/thr)
__global__ __launch_bounds__(256) void scanA_k(const int* __restrict__ cnt,
                                               int* __restrict__ bsum, int n) {
  const int b = blockIdx.x, t = threadIdx.x;
  const int i0 = b * SCH + t * 4;
  int s = 0;
  #pragma unroll
  for (int j = 0; j < 4; ++j) s += (i0 + j < n) ? cnt[i0 + j] : 0;
  #pragma unroll
  for (int d = 1; d < 64; d <<= 1) s += __shfl_xor(s, d);
  __shared__ int ws[4];
  if ((t & 63) == 0) ws[t >> 6] = s;
  __syncthreads();
  if (t == 0) bsum[b] = ws[0] + ws[1] + ws[2] + ws[3];
}

// Phase B: inclusive scan of the NSB(=98) chunk sums, in place (1 block, 128 thr)
__global__ __launch_bounds__(128) void scanB_k(int* __restrict__ bsum, int nb) {
  const int t = threadIdx.x;
  int v = (t < nb) ? bsum[t] : 0;
  const int lane = t & 63, w = t >> 6;
  #pragma unroll
  for (int d = 1; d < 64; d <<= 1) {
    int u = __shfl_up(v, d);
    if (lane >= d) v += u;
  }
  __shared__ int wt;
  if (w == 0 && lane == 63) wt = v;
  __syncthreads();
  if (w == 1) v += wt;
  if (t < nb) bsum[t] = v;   // inclusive; consumer uses bsum[b-1]
}

// Phase C: local exclusive scan + chunk base -> off
__global__ __launch_bounds__(256) void scanC_k(const int* __restrict__ cnt,
                                               const int* __restrict__ bsum,
                                               int* __restrict__ off, int n) {
  const int b = blockIdx.x, t = threadIdx.x;
  const int i0 = b * SCH + t * 4;
  int c[4];
  #pragma unroll
  for (int j = 0; j < 4; ++j) c[j] = (i0 + j < n) ? cnt[i0 + j] : 0;
  const int s = c[0] + c[1] + c[2] + c[3];
  const int lane = t & 63, w = t >> 6;
  int v = s;
  #pragma unroll
  for (int d = 1; d < 64; d <<= 1) {
    int u = __shfl_up(v, d);
    if (lane >= d) v += u;
  }
  __shared__ int ws[4];
  if (lane == 63) ws[w] = v;
  __syncthreads();
  int wpre = 0;
  #pragma unroll
  for (int k = 0; k < 4; ++k) if (k < w) wpre += ws[k];
  const int bbase = (b > 0) ? bsum[b - 1] : 0;
  int p = bbase + wpre + v - s;   // exclusive start for this thread's 4 elems
  #pragma unroll
  for (int j = 0; j < 4; ++j) {
    if (i0 + j < n) off[i0 + j] = p;
    p += c[j];
  }
}

// scatter: off[] doubles as the running slot allocator; after this kernel
// off[d] == start(d) + deg(d), so consumers compute start = off[d] - cnt[d].
__global__ __launch_bounds__(256) void scatter_k(const int* __restrict__ dst,
                                                 int* __restrict__ off,
                                                 int* __restrict__ perm, int n) {
  int i = blockIdx.x * blockDim.x + threadIdx.x;
  int stride = gridDim.x * blockDim.x;
  for (; i < n; i += stride) {
    int p = atomicAdd(&off[dst[i]], 1);
    perm[p] = i;
  }
}

// ---------------- GEMM (x @ W) + fused attention dots, fp16 feat out ------
// 128 rows/block, 256 threads; thread (rt=tid>>4, ct=tid&15) computes an
// 8x8 tile (rows rt*8.., cols ct*8..).  LDS 67KB (fp16 W + fp16 x) ->
// 2 blocks/CU.  x-reads: 4 distinct banks + broadcast (free); W-read: one
// 16B h8 per k, 2-way (free).

template <int H>
__global__ __launch_bounds__(256) void gemm_attn_k(
    const float* __restrict__ x, const float* __restrict__ W,
    const float* __restrict__ al, const float* __restrict__ ar,
    f16* __restrict__ feat, float* __restrict__ el, float* __restrict__ er,
    int n) {
  __shared__ f16 sW[DIM * DIM];   // 32 KB, [k][n]
  __shared__ f16 sx[DIM * 133];   // 34 KB, [r][k] stride 133
  const int tid = threadIdx.x;
  const int row0 = blockIdx.x * DIM;
  for (int i = tid; i < DIM * 32; i += 256) {
    float4 v = ((const float4*)W)[i];
    f16* p = sW + i * 4;
    p[0] = (f16)v.x; p[1] = (f16)v.y; p[2] = (f16)v.z; p[3] = (f16)v.w;
  }
  for (int i = tid; i < DIM * 32; i += 256) {
    int r = i >> 5, c4 = (i & 31) * 4;
    int gr = row0 + r;
    float4 v = make_float4(0.f, 0.f, 0.f, 0.f);
    if (gr < n) v = ((const float4*)(x + (size_t)gr * DIM))[i & 31];
    f16* p = sx + r * 133 + c4;
    p[0] = (f16)v.x; p[1] = (f16)v.y; p[2] = (f16)v.z; p[3] = (f16)v.w;
  }
  __syncthreads();
  const int rt = tid >> 4, ct = tid & 15;
  float acc[8][8];
  #pragma unroll
  for (int j = 0; j < 8; ++j)
    #pragma unroll
    for (int c = 0; c < 8; ++c) acc[j][c] = 0.f;
  const f16* xb = sx + rt * 8 * 133;
  const f16* wb = sW + ct * 8;
  #pragma unroll 2
  for (int k = 0; k < DIM; ++k) {
    float xv[8];
    #pragma unroll
    for (int j = 0; j < 8; ++j) xv[j] = (float)xb[j * 133 + k];
    h8 wv = *(const h8*)(wb + k * DIM);
    float wf[8];
    #pragma unroll
    for (int c = 0; c < 8; ++c) wf[c] = (float)wv.v[c];
    #pragma unroll
    for (int j = 0; j < 8; ++j)
      #pragma unroll
      for (int c = 0; c < 8; ++c)
        acc[j][c] = fmaf(xv[j], wf[c], acc[j][c]);
  }
  // epilogue: fp16 feat store + attention dot reductions
  float alv[8], arv[8];
  #pragma unroll
  for (int c = 0; c < 8; ++c) { alv[c] = al[ct * 8 + c]; arv[c] = ar[ct * 8 + c]; }
  const int RED = (H == 4) ? 4 : 16;  // ct-group size per head
  const int gbase = row0 + rt * 8;
  #pragma unroll
  for (int j = 0; j < 8; ++j) {
    int gr = gbase + j;
    bool ok = gr < n;
    h8 o;
    float pl = 0.f, pr = 0.f;
    #pragma unroll
    for (int c = 0; c < 8; ++c) {
      o.v[c] = (f16)acc[j][c];
      pl = fmaf(acc[j][c], alv[c], pl);
      pr = fmaf(acc[j][c], arv[c], pr);
    }
    if (ok) *(h8*)(feat + (size_t)gr * DIM + ct * 8) = o;
    #pragma unroll
    for (int d = 1; d < RED; d <<= 1) {
      pl += __shfl_xor(pl, d);
      pr += __shfl_xor(pr, d);
    }
    if (ok && (ct % RED) == 0) {
      int hh = ct / RED;
      el[gr * H + hh] = pl;
      er[gr * H + hh] = pr;
    }
  }
}

// ---------------- edge softmax + aggregate, layer 1 (H=4, F=32) ----------
// one wave/node; 16-edge chunks; fixed-trip unrolled gather for MLP.
// off[] is post-scatter: start = off[wid] - deg.

__global__ __launch_bounds__(256) void edge1_k(
    const f16* __restrict__ feat, const float* __restrict__ el,
    const float* __restrict__ er, const float* __restrict__ bias,
    const int* __restrict__ off, const int* __restrict__ cnt,
    const int* __restrict__ perm, const int* __restrict__ src,
    float* __restrict__ hout, int n_nodes) {
  const int wid = (int)((blockIdx.x * blockDim.x + threadIdx.x) >> 6);
  const int lane = threadIdx.x & 63;
  if (wid >= n_nodes) return;
  const int deg = cnt[wid], start = off[wid] - deg;
  const int eL = lane >> 2, hh = lane & 3;   // weight phase: 16 edges x 4 heads
  const float er_h = er[wid * 4 + hh];
  const int h2 = lane >> 4;                  // gather phase: head (f-slice 2*lane)
  const int f0 = lane * 2;
  float acc0 = 0.f, acc1 = 0.f, s_part = 0.f;
  for (int c0 = 0; c0 < deg; c0 += 16) {
    int i = c0 + eL;
    bool val = i < deg;
    int e = perm[start + (val ? i : 0)];
    int sidx = val ? src[e] : 0;
    float v = el[sidx * 4 + hh] + er_h;
    v = (v >= 0.f) ? v : 0.2f * v;
    float w = val ? __expf(v) : 0.f;
    s_part += w;
    #pragma unroll
    for (int j = 0; j < 16; ++j) {
      int se = __shfl(sidx, j * 4);
      float we = __shfl(w, j * 4 + h2);
      union { unsigned u; f16 h[2]; } cv;
      cv.u = *(const unsigned*)(feat + (size_t)se * DIM + f0);
      acc0 = fmaf(we, (float)cv.h[0], acc0);
      acc1 = fmaf(we, (float)cv.h[1], acc1);
    }
  }
  #pragma unroll
  for (int d = 4; d < 64; d <<= 1) s_part += __shfl_xor(s_part, d);
  float s_tot = __shfl(s_part, h2);  // lane h2 (<4) has eL==0, hh==h2
  float inv = (deg > 0) ? 1.0f / s_tot : 0.f;
  float2 bv = *(const float2*)(bias + f0);
  float o0 = fmaxf(fmaf(acc0, inv, bv.x), 0.f);
  float o1 = fmaxf(fmaf(acc1, inv, bv.y), 0.f);
  *(float2*)(hout + (size_t)wid * DIM + f0) = make_float2(o0, o1);
}

// ---------------- edge softmax + aggregate, layer 2 (H=1) + fused FC -----

__global__ __launch_bounds__(256) void edge2_k(
    const f16* __restrict__ feat, const float* __restrict__ el,
    const float* __restrict__ er, const float* __restrict__ bias,
    const float* __restrict__ fcW, const float* __restrict__ fcb,
    const float* __restrict__ thres,
    const int* __restrict__ off, const int* __restrict__ cnt,
    const int* __restrict__ perm, const int* __restrict__ src,
    float* __restrict__ out, int n_nodes) {
  const int wid = (int)((blockIdx.x * blockDim.x + threadIdx.x) >> 6);
  const int lane = threadIdx.x & 63;
  if (wid >= n_nodes) return;
  const int deg = cnt[wid], start = off[wid] - deg;
  const float ern = er[wid];
  const int eI = lane & 15;
  const int f0 = lane * 2;
  float acc0 = 0.f, acc1 = 0.f, s_part = 0.f;
  for (int c0 = 0; c0 < deg; c0 += 16) {
    int i = c0 + eI;
    bool val = i < deg;
    int e = perm[start + (val ? i : 0)];
    int sidx = val ? src[e] : 0;
    float v = el[sidx] + ern;
    v = (v >= 0.f) ? v : 0.2f * v;
    float w = val ? __expf(v) : 0.f;
    s_part += w;
    #pragma unroll
    for (int j = 0; j < 16; ++j) {
      int se = __shfl(sidx, j);
      float we = __shfl(w, j);
      union { unsigned u; f16 h[2]; } cv;
      cv.u = *(const unsigned*)(feat + (size_t)se * DIM + f0);
      acc0 = fmaf(we, (float)cv.h[0], acc0);
      acc1 = fmaf(we, (float)cv.h[1], acc1);
    }
  }
  #pragma unroll
  for (int d = 1; d < 16; d <<= 1) s_part += __shfl_xor(s_part, d);
  float inv = (deg > 0) ? 1.f / s_part : 0.f;
  float o0 = fmaf(acc0, inv, bias[f0]);
  float o1 = fmaf(acc1, inv, bias[f0 + 1]);
  float p = o0 * fcW[f0] + o1 * fcW[f0 + 1];
  #pragma unroll
  for (int d = 1; d < 64; d <<= 1) p += __shfl_xor(p, d);
  if (lane == 0) out[wid] = p + fcb[0] - thres[0];
}

// ---------------- launch ----------------

extern "C" void kernel_launch(void* const* d_in, const int* in_sizes, int n_in,
                              void* d_out, int out_size, void* d_ws, size_t ws_size,
                              hipStream_t stream) {
  const float* features = (const float*)d_in[0];
  const float* W1   = (const float*)d_in[1];
  const float* al1  = (const float*)d_in[2];
  const float* ar1  = (const float*)d_in[3];
  const float* b1   = (const float*)d_in[4];
  const float* W2   = (const float*)d_in[5];
  const float* al2  = (const float*)d_in[6];
  const float* ar2  = (const float*)d_in[7];
  const float* b2   = (const float*)d_in[8];
  const float* fcW  = (const float*)d_in[9];
  const float* fcb  = (const float*)d_in[10];
  const float* thr  = (const float*)d_in[11];
  const int*   src  = (const int*)d_in[12];
  const int*   dst  = (const int*)d_in[13];
  float* out = (float*)d_out;

  char* ws = (char*)d_ws;
  size_t o = 0;
  auto alloc = [&](size_t bytes) -> void* {
    void* p = (void*)(ws + o);
    o += (bytes + 255) & ~(size_t)255;
    return p;
  };
  f16*   feat = (f16*)alloc((size_t)NN * DIM * 2);   // layer1 feat, reused layer2
  float* h    = (float*)alloc((size_t)NN * DIM * 4); // layer1 output (fp32)
  float* el1  = (float*)alloc((size_t)NN * 4 * 4);
  float* er1  = (float*)alloc((size_t)NN * 4 * 4);
  float* el2  = (float*)alloc((size_t)NN * 4);
  float* er2  = (float*)alloc((size_t)NN * 4);
  int* cnt  = (int*)alloc((size_t)NN * 4);
  int* offs = (int*)alloc((size_t)NN * 4);
  int* perm = (int*)alloc((size_t)NE * 4);
  int* bsum = (int*)alloc((size_t)NSB * 4);

  hipMemsetAsync(cnt, 0, (size_t)NN * 4, stream);

  const int GB = (NN + DIM - 1) / DIM;  // 782 blocks for GEMM
  hist_k<<<1024, 256, 0, stream>>>(dst, cnt, NE);
  gemm_attn_k<4><<<GB, 256, 0, stream>>>(features, W1, al1, ar1, feat, el1, er1, NN);
  scanA_k<<<NSB, 256, 0, stream>>>(cnt, bsum, NN);
  scanB_k<<<1, 128, 0, stream>>>(bsum, NSB);
  scanC_k<<<NSB, 256, 0, stream>>>(cnt, bsum, offs, NN);
  scatter_k<<<1024, 256, 0, stream>>>(dst, offs, perm, NE);
  edge1_k<<<(NN * 64) / 256, 256, 0, stream>>>(feat, el1, er1, b1, offs, cnt,
                                               perm, src, h, NN);
  gemm_attn_k<1><<<GB, 256, 0, stream>>>(h, W2, al2, ar2, feat, el2, er2, NN);
  edge2_k<<<(NN * 64) / 256, 256, 0, stream>>>(feat, el2, er2, b2, fcW, fcb,
                                               thr, offs, cnt, perm, src, out, NN);
}

// Round 11
// 444.547 us; speedup vs baseline: 2.0891x; 1.4623x over previous
//
#include <hip/hip_runtime.h>
#include <hip/hip_bf16.h>

#define NN 100000
#define NE 1600000
#define DIM 128
#define G 256                         // edge-partition groups (blocks)
#define EPB (NE / G)                  // 6250 edges per group (exact)
#define NBKT 782                      // ceil(NN/128) buckets of 128 nodes
#define L (NBKT * G)                  // 200192 (bucket,group) counters
#define NSB2 ((L + 1023) / 1024)      // 196 scan blocks

typedef _Float16 f16;
struct alignas(16) h8 { f16 v[8]; };

// ---------------- CSR build: 2-level counting sort ----------------
// Bucket = dst>>7 (128 nodes). Output: srcs[] node-grouped, off[NN+1].
// All final writes are single-block-owned & sequential -> no 64B/4B
// write amplification (round-10 scatter_k: WRITE_SIZE 106MB = NE*64B).

// Pass A: per-group bucket histogram -> gcnt[b*G+g]
__global__ __launch_bounds__(256) void bhistA_k(const int* __restrict__ dst,
                                                int* __restrict__ gcnt) {
  __shared__ int h[NBKT];
  const int g = blockIdx.x, t = threadIdx.x;
  for (int b = t; b < NBKT; b += 256) h[b] = 0;
  __syncthreads();
  const int e0 = g * EPB;
  for (int i = t; i < EPB; i += 256) atomicAdd(&h[dst[e0 + i] >> 7], 1);
  __syncthreads();
  for (int b = t; b < NBKT; b += 256) gcnt[b * G + g] = h[b];
}

// Scan phase A: per-chunk sums (1024 elems/block)
__global__ __launch_bounds__(256) void scanA_k(const int* __restrict__ cnt,
                                               int* __restrict__ bsum, int n) {
  const int b = blockIdx.x, t = threadIdx.x;
  const int i0 = b * 1024 + t * 4;
  int s = 0;
  #pragma unroll
  for (int j = 0; j < 4; ++j) s += (i0 + j < n) ? cnt[i0 + j] : 0;
  #pragma unroll
  for (int d = 1; d < 64; d <<= 1) s += __shfl_xor(s, d);
  __shared__ int ws[4];
  if ((t & 63) == 0) ws[t >> 6] = s;
  __syncthreads();
  if (t == 0) bsum[b] = ws[0] + ws[1] + ws[2] + ws[3];
}

// Scan phase B: inclusive scan of nb (<=256) chunk sums, 4 waves
__global__ __launch_bounds__(256) void scanB2_k(int* __restrict__ bsum, int nb) {
  const int t = threadIdx.x;
  int v = (t < nb) ? bsum[t] : 0;
  const int lane = t & 63, w = t >> 6;
  #pragma unroll
  for (int d = 1; d < 64; d <<= 1) {
    int u = __shfl_up(v, d);
    if (lane >= d) v += u;
  }
  __shared__ int ws[4];
  if (lane == 63) ws[w] = v;
  __syncthreads();
  int pre = 0;
  #pragma unroll
  for (int k = 0; k < 4; ++k) if (k < w) pre += ws[k];
  v += pre;
  if (t < nb) bsum[t] = v;   // inclusive; consumer uses bsum[b-1]
}

// Scan phase C: local exclusive scan + chunk base -> S
__global__ __launch_bounds__(256) void scanC_k(const int* __restrict__ cnt,
                                               const int* __restrict__ bsum,
                                               int* __restrict__ off, int n) {
  const int b = blockIdx.x, t = threadIdx.x;
  const int i0 = b * 1024 + t * 4;
  int c[4];
  #pragma unroll
  for (int j = 0; j < 4; ++j) c[j] = (i0 + j < n) ? cnt[i0 + j] : 0;
  const int s = c[0] + c[1] + c[2] + c[3];
  const int lane = t & 63, w = t >> 6;
  int v = s;
  #pragma unroll
  for (int d = 1; d < 64; d <<= 1) {
    int u = __shfl_up(v, d);
    if (lane >= d) v += u;
  }
  __shared__ int ws[4];
  if (lane == 63) ws[w] = v;
  __syncthreads();
  int wpre = 0;
  #pragma unroll
  for (int k = 0; k < 4; ++k) if (k < w) wpre += ws[k];
  const int bbase = (b > 0) ? bsum[b - 1] : 0;
  int p = bbase + wpre + v - s;
  #pragma unroll
  for (int j = 0; j < 4; ++j) {
    if (i0 + j < n) off[i0 + j] = p;
    p += c[j];
  }
}

// Pass C: group scatter into per-(g,b) sub-segments; packed = (dst&127)<<17|src
__global__ __launch_bounds__(256) void bscatC_k(const int* __restrict__ dst,
                                                const int* __restrict__ src,
                                                const int* __restrict__ S,
                                                int* __restrict__ packed) {
  __shared__ int r[NBKT];
  const int g = blockIdx.x, t = threadIdx.x;
  for (int b = t; b < NBKT; b += 256) r[b] = S[b * G + g];
  __syncthreads();
  const int e0 = g * EPB;
  for (int i = t; i < EPB; i += 256) {
    int d = dst[e0 + i], s = src[e0 + i];
    int pos = atomicAdd(&r[d >> 7], 1);
    packed[pos] = ((d & 127) << 17) | s;
  }
}

// Pass D: per-bucket node sort -> off[] + srcs[] (single-block-owned writes)
__global__ __launch_bounds__(256) void bsortD_k(const int* __restrict__ S,
                                                const int* __restrict__ packed,
                                                int* __restrict__ off,
                                                int* __restrict__ srcs,
                                                int n_nodes) {
  __shared__ int hist[128], r2[128], ws[4];
  const int b = blockIdx.x, t = threadIdx.x;
  const int bbase = S[b * G];
  const int bend = (b == NBKT - 1) ? NE : S[(b + 1) * G];
  const int n_b = bend - bbase;
  if (t < 128) hist[t] = 0;
  __syncthreads();
  for (int i = t; i < n_b; i += 256) atomicAdd(&hist[packed[bbase + i] >> 17], 1);
  __syncthreads();
  // inclusive scan of hist[0..127] (threads >=128 contribute 0)
  const int own = (t < 128) ? hist[t] : 0;
  int v = own;
  const int lane = t & 63, w = t >> 6;
  #pragma unroll
  for (int d = 1; d < 64; d <<= 1) {
    int u = __shfl_up(v, d);
    if (lane >= d) v += u;
  }
  if (lane == 63) ws[w] = v;
  __syncthreads();
  int pre = 0;
  #pragma unroll
  for (int k = 0; k < 4; ++k) if (k < w) pre += ws[k];
  v += pre;
  const int exc = v - own;   // exclusive local node start
  const int nloc = min(128, n_nodes - b * 128);
  if (t < nloc) { off[b * 128 + t] = bbase + exc; r2[t] = exc; }
  if (b == NBKT - 1 && t == 0) off[n_nodes] = NE;
  __syncthreads();
  for (int i = t; i < n_b; i += 256) {
    int p = packed[bbase + i];
    int pos = atomicAdd(&r2[p >> 17], 1);
    srcs[bbase + pos] = p & 0x1FFFF;
  }
}

// ---------------- GEMM (x @ W) + fused attention dots, fp16 feat out ------
// 128 rows/block, 256 threads; thread (rt=tid>>4, ct=tid&15) computes an
// 8x8 tile.  LDS 67KB (fp16 W + fp16 x) -> 2 blocks/CU.

template <int H>
__global__ __launch_bounds__(256) void gemm_attn_k(
    const float* __restrict__ x, const float* __restrict__ W,
    const float* __restrict__ al, const float* __restrict__ ar,
    f16* __restrict__ feat, float* __restrict__ el, float* __restrict__ er,
    int n) {
  __shared__ f16 sW[DIM * DIM];   // 32 KB, [k][n]
  __shared__ f16 sx[DIM * 133];   // 34 KB, [r][k] stride 133
  const int tid = threadIdx.x;
  const int row0 = blockIdx.x * DIM;
  for (int i = tid; i < DIM * 32; i += 256) {
    float4 v = ((const float4*)W)[i];
    f16* p = sW + i * 4;
    p[0] = (f16)v.x; p[1] = (f16)v.y; p[2] = (f16)v.z; p[3] = (f16)v.w;
  }
  for (int i = tid; i < DIM * 32; i += 256) {
    int r = i >> 5, c4 = (i & 31) * 4;
    int gr = row0 + r;
    float4 v = make_float4(0.f, 0.f, 0.f, 0.f);
    if (gr < n) v = ((const float4*)(x + (size_t)gr * DIM))[i & 31];
    f16* p = sx + r * 133 + c4;
    p[0] = (f16)v.x; p[1] = (f16)v.y; p[2] = (f16)v.z; p[3] = (f16)v.w;
  }
  __syncthreads();
  const int rt = tid >> 4, ct = tid & 15;
  float acc[8][8];
  #pragma unroll
  for (int j = 0; j < 8; ++j)
    #pragma unroll
    for (int c = 0; c < 8; ++c) acc[j][c] = 0.f;
  const f16* xb = sx + rt * 8 * 133;
  const f16* wb = sW + ct * 8;
  #pragma unroll 2
  for (int k = 0; k < DIM; ++k) {
    float xv[8];
    #pragma unroll
    for (int j = 0; j < 8; ++j) xv[j] = (float)xb[j * 133 + k];
    h8 wv = *(const h8*)(wb + k * DIM);
    float wf[8];
    #pragma unroll
    for (int c = 0; c < 8; ++c) wf[c] = (float)wv.v[c];
    #pragma unroll
    for (int j = 0; j < 8; ++j)
      #pragma unroll
      for (int c = 0; c < 8; ++c)
        acc[j][c] = fmaf(xv[j], wf[c], acc[j][c]);
  }
  float alv[8], arv[8];
  #pragma unroll
  for (int c = 0; c < 8; ++c) { alv[c] = al[ct * 8 + c]; arv[c] = ar[ct * 8 + c]; }
  const int RED = (H == 4) ? 4 : 16;
  const int gbase = row0 + rt * 8;
  #pragma unroll
  for (int j = 0; j < 8; ++j) {
    int gr = gbase + j;
    bool ok = gr < n;
    h8 o;
    float pl = 0.f, pr = 0.f;
    #pragma unroll
    for (int c = 0; c < 8; ++c) {
      o.v[c] = (f16)acc[j][c];
      pl = fmaf(acc[j][c], alv[c], pl);
      pr = fmaf(acc[j][c], arv[c], pr);
    }
    if (ok) *(h8*)(feat + (size_t)gr * DIM + ct * 8) = o;
    #pragma unroll
    for (int d = 1; d < RED; d <<= 1) {
      pl += __shfl_xor(pl, d);
      pr += __shfl_xor(pr, d);
    }
    if (ok && (ct % RED) == 0) {
      int hh = ct / RED;
      el[gr * H + hh] = pl;
      er[gr * H + hh] = pr;
    }
  }
}

// ---------------- edge softmax + aggregate, layer 1 (H=4, F=32) ----------
// one wave/node; srcs[] node-grouped; deg = off[wid+1]-off[wid].

__global__ __launch_bounds__(256) void edge1_k(
    const f16* __restrict__ feat, const float* __restrict__ el,
    const float* __restrict__ er, const float* __restrict__ bias,
    const int* __restrict__ off, const int* __restrict__ srcs,
    float* __restrict__ hout, int n_nodes) {
  const int wid = (int)((blockIdx.x * blockDim.x + threadIdx.x) >> 6);
  const int lane = threadIdx.x & 63;
  if (wid >= n_nodes) return;
  const int start = off[wid], deg = off[wid + 1] - start;
  const int eL = lane >> 2, hh = lane & 3;   // weight phase: 16 edges x 4 heads
  const float er_h = er[wid * 4 + hh];
  const int h2 = lane >> 4;                  // gather phase: head (f-slice 2*lane)
  const int f0 = lane * 2;
  float acc0 = 0.f, acc1 = 0.f, s_part = 0.f;
  for (int c0 = 0; c0 < deg; c0 += 16) {
    int i = c0 + eL;
    bool val = i < deg;
    int sidx = srcs[start + (val ? i : 0)];
    float v = el[sidx * 4 + hh] + er_h;
    v = (v >= 0.f) ? v : 0.2f * v;
    float w = val ? __expf(v) : 0.f;
    s_part += w;
    #pragma unroll
    for (int j = 0; j < 16; ++j) {
      int se = __shfl(sidx, j * 4);
      float we = __shfl(w, j * 4 + h2);
      union { unsigned u; f16 h[2]; } cv;
      cv.u = *(const unsigned*)(feat + (size_t)se * DIM + f0);
      acc0 = fmaf(we, (float)cv.h[0], acc0);
      acc1 = fmaf(we, (float)cv.h[1], acc1);
    }
  }
  #pragma unroll
  for (int d = 4; d < 64; d <<= 1) s_part += __shfl_xor(s_part, d);
  float s_tot = __shfl(s_part, h2);
  float inv = (deg > 0) ? 1.0f / s_tot : 0.f;
  float2 bv = *(const float2*)(bias + f0);
  float o0 = fmaxf(fmaf(acc0, inv, bv.x), 0.f);
  float o1 = fmaxf(fmaf(acc1, inv, bv.y), 0.f);
  *(float2*)(hout + (size_t)wid * DIM + f0) = make_float2(o0, o1);
}

// ---------------- edge softmax + aggregate, layer 2 (H=1) + fused FC -----

__global__ __launch_bounds__(256) void edge2_k(
    const f16* __restrict__ feat, const float* __restrict__ el,
    const float* __restrict__ er, const float* __restrict__ bias,
    const float* __restrict__ fcW, const float* __restrict__ fcb,
    const float* __restrict__ thres,
    const int* __restrict__ off, const int* __restrict__ srcs,
    float* __restrict__ out, int n_nodes) {
  const int wid = (int)((blockIdx.x * blockDim.x + threadIdx.x) >> 6);
  const int lane = threadIdx.x & 63;
  if (wid >= n_nodes) return;
  const int start = off[wid], deg = off[wid + 1] - start;
  const float ern = er[wid];
  const int eI = lane & 15;
  const int f0 = lane * 2;
  float acc0 = 0.f, acc1 = 0.f, s_part = 0.f;
  for (int c0 = 0; c0 < deg; c0 += 16) {
    int i = c0 + eI;
    bool val = i < deg;
    int sidx = srcs[start + (val ? i : 0)];
    float v = el[sidx] + ern;
    v = (v >= 0.f) ? v : 0.2f * v;
    float w = val ? __expf(v) : 0.f;
    s_part += w;
    #pragma unroll
    for (int j = 0; j < 16; ++j) {
      int se = __shfl(sidx, j);
      float we = __shfl(w, j);
      union { unsigned u; f16 h[2]; } cv;
      cv.u = *(const unsigned*)(feat + (size_t)se * DIM + f0);
      acc0 = fmaf(we, (float)cv.h[0], acc0);
      acc1 = fmaf(we, (float)cv.h[1], acc1);
    }
  }
  #pragma unroll
  for (int d = 1; d < 16; d <<= 1) s_part += __shfl_xor(s_part, d);
  float inv = (deg > 0) ? 1.f / s_part : 0.f;
  float o0 = fmaf(acc0, inv, bias[f0]);
  float o1 = fmaf(acc1, inv, bias[f0 + 1]);
  float p = o0 * fcW[f0] + o1 * fcW[f0 + 1];
  #pragma unroll
  for (int d = 1; d < 64; d <<= 1) p += __shfl_xor(p, d);
  if (lane == 0) out[wid] = p + fcb[0] - thres[0];
}

// ---------------- launch ----------------

extern "C" void kernel_launch(void* const* d_in, const int* in_sizes, int n_in,
                              void* d_out, int out_size, void* d_ws, size_t ws_size,
                              hipStream_t stream) {
  const float* features = (const float*)d_in[0];
  const float* W1   = (const float*)d_in[1];
  const float* al1  = (const float*)d_in[2];
  const float* ar1  = (const float*)d_in[3];
  const float* b1   = (const float*)d_in[4];
  const float* W2   = (const float*)d_in[5];
  const float* al2  = (const float*)d_in[6];
  const float* ar2  = (const float*)d_in[7];
  const float* b2   = (const float*)d_in[8];
  const float* fcW  = (const float*)d_in[9];
  const float* fcb  = (const float*)d_in[10];
  const float* thr  = (const float*)d_in[11];
  const int*   src  = (const int*)d_in[12];
  const int*   dst  = (const int*)d_in[13];
  float* out = (float*)d_out;

  char* ws = (char*)d_ws;
  size_t o = 0;
  auto alloc = [&](size_t bytes) -> void* {
    void* p = (void*)(ws + o);
    o += (bytes + 255) & ~(size_t)255;
    return p;
  };
  f16*   feat = (f16*)alloc((size_t)NN * DIM * 2);   // layer1 feat, reused layer2
  float* h    = (float*)alloc((size_t)NN * DIM * 4); // layer1 output (fp32)
  float* el1  = (float*)alloc((size_t)NN * 4 * 4);
  float* er1  = (float*)alloc((size_t)NN * 4 * 4);
  float* el2  = (float*)alloc((size_t)NN * 4);
  float* er2  = (float*)alloc((size_t)NN * 4);
  int* gcnt   = (int*)alloc((size_t)L * 4);
  int* S      = (int*)alloc((size_t)L * 4);
  int* bsum2  = (int*)alloc((size_t)NSB2 * 4);
  int* packed = (int*)alloc((size_t)NE * 4);
  int* srcs   = (int*)alloc((size_t)NE * 4);
  int* offs   = (int*)alloc((size_t)(NN + 1) * 4);

  const int GB = (NN + DIM - 1) / DIM;  // 782 blocks for GEMM
  bhistA_k<<<G, 256, 0, stream>>>(dst, gcnt);
  gemm_attn_k<4><<<GB, 256, 0, stream>>>(features, W1, al1, ar1, feat, el1, er1, NN);
  scanA_k<<<NSB2, 256, 0, stream>>>(gcnt, bsum2, L);
  scanB2_k<<<1, 256, 0, stream>>>(bsum2, NSB2);
  scanC_k<<<NSB2, 256, 0, stream>>>(gcnt, bsum2, S, L);
  bscatC_k<<<G, 256, 0, stream>>>(dst, src, S, packed);
  bsortD_k<<<NBKT, 256, 0, stream>>>(S, packed, offs, srcs, NN);
  edge1_k<<<(NN * 64) / 256, 256, 0, stream>>>(feat, el1, er1, b1, offs, srcs, h, NN);
  gemm_attn_k<1><<<GB, 256, 0, stream>>>(h, W2, al2, ar2, feat, el2, er2, NN);
  edge2_k<<<(NN * 64) / 256, 256, 0, stream>>>(feat, el2, er2, b2, fcW, fcb,
                                               thr, offs, srcs, out, NN);
}